// Round 4
// baseline (223.490 us; speedup 1.0000x reference)
//
#include <hip/hip_runtime.h>
#include <cstdint>
#include <math.h>

typedef _Float16 f16;
typedef _Float16 f16x2 __attribute__((ext_vector_type(2)));
typedef _Float16 f16x4 __attribute__((ext_vector_type(4)));
typedef _Float16 f16x8 __attribute__((ext_vector_type(8)));
typedef __fp16   h16x2 __attribute__((ext_vector_type(2)));
typedef float    f32x4 __attribute__((ext_vector_type(4)));

__device__ __forceinline__ f32x4 mfma16(f16x8 a, f16x8 b, f32x4 c) {
  return __builtin_amdgcn_mfma_f32_16x16x32_f16(a, b, c, 0, 0, 0);
}
__device__ __forceinline__ void gl2lds16(const f16* g, f16* l) {
  __builtin_amdgcn_global_load_lds((__attribute__((address_space(1))) void*)(g),
                                   (__attribute__((address_space(3))) void*)(l),
                                   16, 0, 0);
}
__device__ __forceinline__ float fexp2(float x) { return __builtin_amdgcn_exp2f(x); }
__device__ __forceinline__ f16x2 pkrtz(float a, float b) {
  h16x2 r = __builtin_amdgcn_cvt_pkrtz(a, b);
  return __builtin_bit_cast(f16x2, r);
}
__device__ __forceinline__ float dot2acc(f16x2 a, f16x2 b, float c) {
#if __has_builtin(__builtin_amdgcn_fdot2)
  return __builtin_amdgcn_fdot2(__builtin_bit_cast(h16x2, a),
                                __builtin_bit_cast(h16x2, b), c, false);
#else
  return c + (float)a[0] * (float)b[0] + (float)a[1] * (float)b[1];
#endif
}

// ---------------- fp32 -> f16 conversion ----------------
__global__ __launch_bounds__(256) void cvt_kernel(
    const float* __restrict__ x,  const float* __restrict__ wq, const float* __restrict__ wk,
    const float* __restrict__ wv, const float* __restrict__ wo,
    f16* __restrict__ xh, f16* __restrict__ wqkvh, f16* __restrict__ woh)
{
  const int seg = blockIdx.y;
  const float* src; f16* dst; int n;
  if      (seg == 0) { src = x;  dst = xh;              n = 4194304; }
  else if (seg == 1) { src = wq; dst = wqkvh;           n = 1048576; }
  else if (seg == 2) { src = wk; dst = wqkvh + 1048576; n = 1048576; }
  else if (seg == 3) { src = wv; dst = wqkvh + 2097152; n = 1048576; }
  else               { src = wo; dst = woh;             n = 1048576; }
  const int idx = (int)(blockIdx.x * 256 + threadIdx.x) * 8;
  if (idx >= n) return;
  f32x4 a = *(const f32x4*)(src + idx);
  f32x4 b = *(const f32x4*)(src + idx + 4);
  f16x8 h;
  h[0] = (f16)a[0]; h[1] = (f16)a[1]; h[2] = (f16)a[2]; h[3] = (f16)a[3];
  h[4] = (f16)b[0]; h[5] = (f16)b[1]; h[6] = (f16)b[2]; h[7] = (f16)b[3];
  *(f16x8*)(dst + idx) = h;
}

// ---------------- QKV GEMM: 128x128 tile, BK=32 ----------------
// A=[4096x1024]=x, B=[3072x1024]=Wq|Wk|Wv -> Q/K/V [B,H,S,64] f16 (+bias; Q pre-scaled)
__global__ __launch_bounds__(256) void gemm_qkv(
    const f16* __restrict__ A, const f16* __restrict__ B,
    const float* __restrict__ bias0, const float* __restrict__ bias1, const float* __restrict__ bias2,
    f16* __restrict__ Qp, f16* __restrict__ Kp, f16* __restrict__ Vp)
{
  constexpr int K = 1024;
  __shared__ __align__(16) f16 As[128 * 32];
  __shared__ __align__(16) f16 Bs[128 * 32];
  const int tid  = threadIdx.x;
  const int wave = tid >> 6, lane = tid & 63;
  const int quad = lane >> 4, col = lane & 15;
  const int tile_m = blockIdx.y * 128, tile_n = blockIdx.x * 128;
  const int mb = (wave >> 1) * 64, nb = (wave & 1) * 64;
  const int srow = lane >> 2, scol = (lane & 3) * 8;
  const f16* gA = A + (size_t)(tile_m + wave * 32 + srow) * K + scol;
  const f16* gB = B + (size_t)(tile_n + wave * 32 + srow) * K + scol;
  f16* lA = As + wave * 1024;
  f16* lB = Bs + wave * 1024;

  f32x4 acc[4][4] = {};
  for (int k0 = 0; k0 < K; k0 += 32) {
    gl2lds16(gA + k0,          lA);
    gl2lds16(gA + 16 * K + k0, lA + 512);
    gl2lds16(gB + k0,          lB);
    gl2lds16(gB + 16 * K + k0, lB + 512);
    __syncthreads();
    f16x8 af[4], bf[4];
    #pragma unroll
    for (int i = 0; i < 4; ++i)
      af[i] = *(const f16x8*)&As[(mb + i * 16 + col) * 32 + quad * 8];
    #pragma unroll
    for (int j = 0; j < 4; ++j)
      bf[j] = *(const f16x8*)&Bs[(nb + j * 16 + col) * 32 + quad * 8];
    #pragma unroll
    for (int i = 0; i < 4; ++i)
      #pragma unroll
      for (int j = 0; j < 4; ++j)
        acc[i][j] = mfma16(af[i], bf[j], acc[i][j]);
    __syncthreads();
  }

  #pragma unroll
  for (int j = 0; j < 4; ++j) {
    const int gn = tile_n + nb + j * 16 + col;
    const int which = gn >> 10;
    const int d = gn & 1023;
    const float* bp = (which == 0) ? bias0 : (which == 1) ? bias1 : bias2;
    f16* dst        = (which == 0) ? Qp    : (which == 1) ? Kp    : Vp;
    const float bvv = bp[d];
    const float qs  = (which == 0) ? 0.18033688f : 1.0f;  // 1/sqrt(64)*log2(e) folded into Q
    const int h = d >> 6, hi = d & 63;
    #pragma unroll
    for (int i = 0; i < 4; ++i) {
      #pragma unroll
      for (int r = 0; r < 4; ++r) {
        const int gm = tile_m + mb + i * 16 + quad * 4 + r;
        const int bb = gm >> 11, s = gm & 2047;
        dst[(((size_t)bb * 16 + h) * 2048 + s) * 64 + hi] = (f16)((acc[i][j][r] + bvv) * qs);
      }
    }
  }
}

// ---------------- V transpose: [B,H,S,64] -> [B,H,64,S] ----------------
__global__ __launch_bounds__(256) void vtrans_kernel(
    const f16* __restrict__ Vh, f16* __restrict__ Vt)
{
  __shared__ __align__(16) f16 t[64][72];
  const int bh = blockIdx.y;
  const int s0 = blockIdx.x * 64;
  const int tid = threadIdx.x;
  const int sr = tid >> 2, dc = (tid & 3) * 16;
  const size_t ib = ((size_t)bh * 2048 + s0 + sr) * 64 + dc;
  f16x8 v0 = *(const f16x8*)&Vh[ib];
  f16x8 v1 = *(const f16x8*)&Vh[ib + 8];
  *(f16x8*)&t[sr][dc]     = v0;
  *(f16x8*)&t[sr][dc + 8] = v1;
  __syncthreads();
  const int d = tid >> 2, sc = (tid & 3) * 16;
  f16x8 o0, o1;
  #pragma unroll
  for (int j = 0; j < 8; ++j) { o0[j] = t[sc + j][d]; o1[j] = t[sc + 8 + j][d]; }
  const size_t ob = ((size_t)bh * 64 + d) * 2048 + s0 + sc;
  *(f16x8*)&Vt[ob]     = o0;
  *(f16x8*)&Vt[ob + 8] = o1;
}

// ---------------- flash attention, S^T orientation, KV=128, swizzled gl2lds ----------------
// Block: 4 waves x 16 q rows = 64-q tile. qt = 31 - bx (heavy-first LPT).
// Pipeline: raw s_barrier + s_waitcnt vmcnt(4); K(t+1) overlaps softmax+PV, V(t+1) overlaps QK.
__global__ __launch_bounds__(256) void attn_kernel(
    const f16* __restrict__ Q, const f16* __restrict__ K, const f16* __restrict__ Vt,
    f16* __restrict__ ctx)
{
  __shared__ __align__(16) f16 Ks[128 * 64];    // [kv][d], XOR-swizzled 16B chunks (8/row)
  __shared__ __align__(16) f16 Vts[64 * 128];   // [d][kv], XOR-swizzled (16/row)
  __shared__ __align__(16) f16 Ps[4 * 2048];    // per-wave P [16 q][128 kv], swizzled
  __shared__ float abuf[4][16];
  __shared__ float lbuf[4][16];

  const int bh = blockIdx.y;
  const int qt = 31 - (int)blockIdx.x;
  const int nIter = (qt + 2) >> 1;
  const int tid = threadIdx.x;
  const int wave = tid >> 6, lane = tid & 63;
  const int quad = lane >> 4, col = lane & 15;
  const int b = bh >> 4, h = bh & 15;
  const size_t base = (size_t)bh * 2048 * 64;
  const size_t vtb  = (size_t)bh * 64 * 2048;
  const int q0 = qt * 64;
  const int qw0 = q0 + wave * 16;

  // Q B-frags (pre-scaled by 0.125*log2e at gemm epilogue)
  const f16x8 bq0 = *(const f16x8*)&Q[base + (size_t)(qw0 + col) * 64 + quad * 8];
  const f16x8 bq1 = *(const f16x8*)&Q[base + (size_t)(qw0 + col) * 64 + 32 + quad * 8];

  // per-lane swizzled global source offsets (16B-chunk granularity)
  int koff[4], voff[4];
  #pragma unroll
  for (int i = 0; i < 4; ++i) {
    const int ci = wave * 256 + i * 64 + lane;
    const int kr = ci >> 3, kc = ci & 7;
    koff[i] = kr * 64 + ((kc ^ (kr & 7)) * 8);
    const int vr = ci >> 4, vc = ci & 15;
    voff[i] = vr * 2048 + ((vc ^ (vr & 15)) * 8);
  }

  f32x4 ctxa[4] = {};
  float m = -INFINITY, l = 0.f;

  const int kx = col & 7;
  const int pbase = wave * 2048 + col * 128;

  // stage tile 0 (K then V; vmcnt groups of 4 each)
  {
    const f16* gk = K + base;
    #pragma unroll
    for (int i = 0; i < 4; ++i) gl2lds16(gk + koff[i], Ks + wave * 2048 + i * 512);
    const f16* gv = Vt + vtb;
    #pragma unroll
    for (int i = 0; i < 4; ++i) gl2lds16(gv + voff[i], Vts + wave * 2048 + i * 512);
  }

  for (int t = 0; t < nIter; ++t) {
    // own K(t) done (4 V-loads may remain in flight) + all waves' K(t) done
    __asm__ volatile("s_waitcnt vmcnt(4)\n\ts_barrier" ::: "memory");

    // S^T = K Q^T : [128 kv][16 q]
    f32x4 s[8];
    #pragma unroll
    for (int jt = 0; jt < 8; ++jt) {
      const int krow = (jt * 16 + col) * 64;
      const f16x8 ak0 = *(const f16x8*)&Ks[krow + ((quad ^ kx) * 8)];
      const f16x8 ak1 = *(const f16x8*)&Ks[krow + (((4 + quad) ^ kx) * 8)];
      f32x4 z = {};
      z = mfma16(ak0, bq0, z);
      s[jt] = mfma16(ak1, bq1, z);
    }

    // all waves finished reading Ks -> safe to overwrite with K(t+1)
    __asm__ volatile("s_barrier" ::: "memory");
    const int tn = (t + 1 < nIter) ? t + 1 : t;   // clamp keeps vmcnt counts uniform
    {
      const f16* gk = K + base + (size_t)tn * 8192;
      #pragma unroll
      for (int i = 0; i < 4; ++i) gl2lds16(gk + koff[i], Ks + wave * 2048 + i * 512);
    }

    if (t == nIter - 1) {  // causal mask (only the diagonal tile)
      #pragma unroll
      for (int jt = 0; jt < 8; ++jt) {
        const int kg = t * 128 + jt * 16 + quad * 4;
        #pragma unroll
        for (int r = 0; r < 4; ++r)
          if (kg + r > qw0 + col) s[jt][r] = -1e30f;
      }
    }

    // online softmax: each lane owns 32 kv of ONE q (= col); reduce in-lane then across quads
    float tm = fmaxf(fmaxf(s[0][0], s[0][1]), fmaxf(s[0][2], s[0][3]));
    #pragma unroll
    for (int jt = 1; jt < 8; ++jt)
      tm = fmaxf(tm, fmaxf(fmaxf(s[jt][0], s[jt][1]), fmaxf(s[jt][2], s[jt][3])));
    tm = fmaxf(tm, __shfl_xor(tm, 16));
    tm = fmaxf(tm, __shfl_xor(tm, 32));

    const float mnew = fmaxf(m, tm);
    const float alpha = fexp2(m - mnew);
    m = mnew;

    float rs = 0.f;
    const f16x2 one2 = {(_Float16)1.f, (_Float16)1.f};
    #pragma unroll
    for (int jt = 0; jt < 8; ++jt) {
      const float p0 = fexp2(s[jt][0] - mnew);
      const float p1 = fexp2(s[jt][1] - mnew);
      const float p2 = fexp2(s[jt][2] - mnew);
      const float p3 = fexp2(s[jt][3] - mnew);
      const f16x2 a01 = pkrtz(p0, p1);
      const f16x2 a23 = pkrtz(p2, p3);
      rs = dot2acc(a01, one2, rs);
      rs = dot2acc(a23, one2, rs);
      f16x4 pw;
      pw[0] = a01[0]; pw[1] = a01[1]; pw[2] = a23[0]; pw[3] = a23[1];
      const int chunk = jt * 2 + (quad >> 1);
      *(f16x4*)&Ps[pbase + ((chunk ^ col) * 8) + (quad & 1) * 4] = pw;  // b64, conflict-free
    }
    rs += __shfl_xor(rs, 16);
    rs += __shfl_xor(rs, 32);
    l = l * alpha + rs;
    if (quad == 0) abuf[wave][col] = alpha;
    __asm__ volatile("s_waitcnt lgkmcnt(0)" ::: "memory");  // drain P + abuf (in-wave)
    const f32x4 av = *(const f32x4*)&abuf[wave][quad * 4];
    #pragma unroll
    for (int jd = 0; jd < 4; ++jd) ctxa[jd] *= av;

    // own V(t) done (K(t+1) still in flight) + all waves' V(t) done
    __asm__ volatile("s_waitcnt vmcnt(4)\n\ts_barrier" ::: "memory");

    // ctx += P V : A = P[q][kv] (LDS), B = Vt[d][kv] (LDS)
    #pragma unroll
    for (int ks = 0; ks < 4; ++ks) {
      const f16x8 ap = *(const f16x8*)&Ps[pbase + (((ks * 4 + quad) ^ col) * 8)];
      #pragma unroll
      for (int jd = 0; jd < 4; ++jd) {
        const int vrow = (jd * 16 + col) * 128;
        const f16x8 bv = *(const f16x8*)&Vts[vrow + (((ks * 4 + quad) ^ col) * 8)];
        ctxa[jd] = mfma16(ap, bv, ctxa[jd]);
      }
    }

    // all waves finished reading Vts -> safe to overwrite with V(t+1)
    __asm__ volatile("s_barrier" ::: "memory");
    {
      const f16* gv = Vt + vtb + tn * 128;
      #pragma unroll
      for (int i = 0; i < 4; ++i) gl2lds16(gv + voff[i], Vts + wave * 2048 + i * 512);
    }
  }

  // epilogue: broadcast l across quads, normalize, store ctx [B,S,D] f16
  if (quad == 0) lbuf[wave][col] = l;
  __asm__ volatile("s_waitcnt lgkmcnt(0)" ::: "memory");
  const f32x4 lv = *(const f32x4*)&lbuf[wave][quad * 4];
  f32x4 inv;
  #pragma unroll
  for (int r = 0; r < 4; ++r) inv[r] = 1.f / lv[r];
  #pragma unroll
  for (int jd = 0; jd < 4; ++jd) {
    #pragma unroll
    for (int r = 0; r < 4; ++r) {
      const int qg = qw0 + quad * 4 + r;
      ctx[((size_t)b * 2048 + qg) * 1024 + h * 64 + jd * 16 + col] = (f16)(ctxa[jd][r] * inv[r]);
    }
  }
}

// ---------------- O projection: 128x64 tile, BK=32 ----------------
__global__ __launch_bounds__(256) void gemm_o(
    const f16* __restrict__ A, const f16* __restrict__ B, const float* __restrict__ bias,
    float* __restrict__ Out)
{
  constexpr int K = 1024;
  __shared__ __align__(16) f16 As[128 * 32];
  __shared__ __align__(16) f16 Bs[64 * 32];
  const int tid  = threadIdx.x;
  const int wave = tid >> 6, lane = tid & 63;
  const int quad = lane >> 4, col = lane & 15;
  const int tile_m = blockIdx.y * 128, tile_n = blockIdx.x * 64;
  const int mb = wave * 32;
  const int srow = lane >> 2, scol = (lane & 3) * 8;
  const f16* gA = A + (size_t)(tile_m + wave * 32 + srow) * K + scol;
  const f16* gB = B + (size_t)(tile_n + wave * 16 + srow) * K + scol;
  f16* lA = As + wave * 1024;
  f16* lB = Bs + wave * 512;

  f32x4 acc[2][4] = {};
  for (int k0 = 0; k0 < K; k0 += 32) {
    gl2lds16(gA + k0,          lA);
    gl2lds16(gA + 16 * K + k0, lA + 512);
    gl2lds16(gB + k0,          lB);
    __syncthreads();
    f16x8 af[2], bf[4];
    #pragma unroll
    for (int i = 0; i < 2; ++i)
      af[i] = *(const f16x8*)&As[(mb + i * 16 + col) * 32 + quad * 8];
    #pragma unroll
    for (int j = 0; j < 4; ++j)
      bf[j] = *(const f16x8*)&Bs[(j * 16 + col) * 32 + quad * 8];
    #pragma unroll
    for (int i = 0; i < 2; ++i)
      #pragma unroll
      for (int j = 0; j < 4; ++j)
        acc[i][j] = mfma16(af[i], bf[j], acc[i][j]);
    __syncthreads();
  }

  #pragma unroll
  for (int j = 0; j < 4; ++j) {
    const int gn = tile_n + j * 16 + col;
    const float bvv = bias[gn];
    #pragma unroll
    for (int i = 0; i < 2; ++i) {
      #pragma unroll
      for (int r = 0; r < 4; ++r) {
        const int gm = tile_m + mb + i * 16 + quad * 4 + r;
        Out[(size_t)gm * 1024 + gn] = acc[i][j][r] + bvv;
      }
    }
  }
}

extern "C" void kernel_launch(void* const* d_in, const int* in_sizes, int n_in,
                              void* d_out, int out_size, void* d_ws, size_t ws_size,
                              hipStream_t stream)
{
  const float* x  = (const float*)d_in[0];
  const float* Wq = (const float*)d_in[1];
  const float* bq = (const float*)d_in[2];
  const float* Wk = (const float*)d_in[3];
  const float* bk = (const float*)d_in[4];
  const float* Wv = (const float*)d_in[5];
  const float* bv = (const float*)d_in[6];
  const float* Wo = (const float*)d_in[7];
  const float* bo = (const float*)d_in[8];
  float* out = (float*)d_out;

  f16* ws = (f16*)d_ws;
  const size_t M1 = 1048576;
  f16* xh    = ws;             // 4M halves
  f16* wqkvh = ws + 4  * M1;   // 3M
  f16* woh   = ws + 7  * M1;   // 1M
  f16* Qh    = ws + 8  * M1;   // 4M  [B,H,S,64] (pre-scaled)
  f16* Kh    = ws + 12 * M1;   // 4M  [B,H,S,64]
  f16* Vh    = ws + 16 * M1;   // 4M  [B,H,S,64]
  f16* Vth   = ws + 20 * M1;   // 4M  [B,H,64,S]
  f16* ctxh  = ws + 24 * M1;   // 4M  [B,S,D]    (total 56 MB)

  cvt_kernel<<<dim3(2048, 5), 256, 0, stream>>>(x, Wq, Wk, Wv, Wo, xh, wqkvh, woh);
  gemm_qkv<<<dim3(24, 32), 256, 0, stream>>>(xh, wqkvh, bq, bk, bv, Qh, Kh, Vh);
  vtrans_kernel<<<dim3(32, 32), 256, 0, stream>>>(Vh, Vth);
  attn_kernel<<<dim3(32, 32), 256, 0, stream>>>(Qh, Kh, Vth, ctxh);
  gemm_o<<<dim3(16, 32), 256, 0, stream>>>(ctxh, woh, bo, out);
}

// Round 5
// 201.978 us; speedup vs baseline: 1.1065x; 1.1065x over previous
//
#include <hip/hip_runtime.h>
#include <cstdint>
#include <math.h>

typedef _Float16 f16;
typedef _Float16 f16x2 __attribute__((ext_vector_type(2)));
typedef _Float16 f16x4 __attribute__((ext_vector_type(4)));
typedef _Float16 f16x8 __attribute__((ext_vector_type(8)));
typedef __fp16   h16x2 __attribute__((ext_vector_type(2)));
typedef float    f32x4 __attribute__((ext_vector_type(4)));

__device__ __forceinline__ f32x4 mfma16(f16x8 a, f16x8 b, f32x4 c) {
  return __builtin_amdgcn_mfma_f32_16x16x32_f16(a, b, c, 0, 0, 0);
}
__device__ __forceinline__ void gl2lds16(const f16* g, f16* l) {
  __builtin_amdgcn_global_load_lds((__attribute__((address_space(1))) void*)(g),
                                   (__attribute__((address_space(3))) void*)(l),
                                   16, 0, 0);
}
__device__ __forceinline__ float fexp2(float x) { return __builtin_amdgcn_exp2f(x); }
__device__ __forceinline__ f16x2 pkrtz(float a, float b) {
  h16x2 r = __builtin_amdgcn_cvt_pkrtz(a, b);
  return __builtin_bit_cast(f16x2, r);
}
__device__ __forceinline__ float dot2acc(f16x2 a, f16x2 b, float c) {
#if __has_builtin(__builtin_amdgcn_fdot2)
  return __builtin_amdgcn_fdot2(__builtin_bit_cast(h16x2, a),
                                __builtin_bit_cast(h16x2, b), c, false);
#else
  return c + (float)a[0] * (float)b[0] + (float)a[1] * (float)b[1];
#endif
}

// ---------------- fp32 -> f16 conversion ----------------
__global__ __launch_bounds__(256) void cvt_kernel(
    const float* __restrict__ x,  const float* __restrict__ wq, const float* __restrict__ wk,
    const float* __restrict__ wv, const float* __restrict__ wo,
    f16* __restrict__ xh, f16* __restrict__ wqkvh, f16* __restrict__ woh)
{
  const int seg = blockIdx.y;
  const float* src; f16* dst; int n;
  if      (seg == 0) { src = x;  dst = xh;              n = 4194304; }
  else if (seg == 1) { src = wq; dst = wqkvh;           n = 1048576; }
  else if (seg == 2) { src = wk; dst = wqkvh + 1048576; n = 1048576; }
  else if (seg == 3) { src = wv; dst = wqkvh + 2097152; n = 1048576; }
  else               { src = wo; dst = woh;             n = 1048576; }
  const int idx = (int)(blockIdx.x * 256 + threadIdx.x) * 8;
  if (idx >= n) return;
  f32x4 a = *(const f32x4*)(src + idx);
  f32x4 b = *(const f32x4*)(src + idx + 4);
  f16x8 h;
  h[0] = (f16)a[0]; h[1] = (f16)a[1]; h[2] = (f16)a[2]; h[3] = (f16)a[3];
  h[4] = (f16)b[0]; h[5] = (f16)b[1]; h[6] = (f16)b[2]; h[7] = (f16)b[3];
  *(f16x8*)(dst + idx) = h;
}

// ---------------- QKV GEMM: 128x128 tile, BK=32 ----------------
__global__ __launch_bounds__(256) void gemm_qkv(
    const f16* __restrict__ A, const f16* __restrict__ B,
    const float* __restrict__ bias0, const float* __restrict__ bias1, const float* __restrict__ bias2,
    f16* __restrict__ Qp, f16* __restrict__ Kp, f16* __restrict__ Vp)
{
  constexpr int K = 1024;
  __shared__ __align__(16) f16 As[128 * 32];
  __shared__ __align__(16) f16 Bs[128 * 32];
  const int tid  = threadIdx.x;
  const int wave = tid >> 6, lane = tid & 63;
  const int quad = lane >> 4, col = lane & 15;
  const int tile_m = blockIdx.y * 128, tile_n = blockIdx.x * 128;
  const int mb = (wave >> 1) * 64, nb = (wave & 1) * 64;
  const int srow = lane >> 2, scol = (lane & 3) * 8;
  const f16* gA = A + (size_t)(tile_m + wave * 32 + srow) * K + scol;
  const f16* gB = B + (size_t)(tile_n + wave * 32 + srow) * K + scol;
  f16* lA = As + wave * 1024;
  f16* lB = Bs + wave * 1024;

  f32x4 acc[4][4] = {};
  for (int k0 = 0; k0 < K; k0 += 32) {
    gl2lds16(gA + k0,          lA);
    gl2lds16(gA + 16 * K + k0, lA + 512);
    gl2lds16(gB + k0,          lB);
    gl2lds16(gB + 16 * K + k0, lB + 512);
    __syncthreads();
    f16x8 af[4], bf[4];
    #pragma unroll
    for (int i = 0; i < 4; ++i)
      af[i] = *(const f16x8*)&As[(mb + i * 16 + col) * 32 + quad * 8];
    #pragma unroll
    for (int j = 0; j < 4; ++j)
      bf[j] = *(const f16x8*)&Bs[(nb + j * 16 + col) * 32 + quad * 8];
    #pragma unroll
    for (int i = 0; i < 4; ++i)
      #pragma unroll
      for (int j = 0; j < 4; ++j)
        acc[i][j] = mfma16(af[i], bf[j], acc[i][j]);
    __syncthreads();
  }

  #pragma unroll
  for (int j = 0; j < 4; ++j) {
    const int gn = tile_n + nb + j * 16 + col;
    const int which = gn >> 10;
    const int d = gn & 1023;
    const float* bp = (which == 0) ? bias0 : (which == 1) ? bias1 : bias2;
    f16* dst        = (which == 0) ? Qp    : (which == 1) ? Kp    : Vp;
    const float bvv = bp[d];
    const float qs  = (which == 0) ? 0.18033688f : 1.0f;  // 1/sqrt(64)*log2(e) folded into Q
    const int h = d >> 6, hi = d & 63;
    #pragma unroll
    for (int i = 0; i < 4; ++i) {
      #pragma unroll
      for (int r = 0; r < 4; ++r) {
        const int gm = tile_m + mb + i * 16 + quad * 4 + r;
        const int bb = gm >> 11, s = gm & 2047;
        dst[(((size_t)bb * 16 + h) * 2048 + s) * 64 + hi] = (f16)((acc[i][j][r] + bvv) * qs);
      }
    }
  }
}

// ---------------- V transpose: [B,H,S,64] -> [B,H,64,S] ----------------
__global__ __launch_bounds__(256) void vtrans_kernel(
    const f16* __restrict__ Vh, f16* __restrict__ Vt)
{
  __shared__ __align__(16) f16 t[64][72];
  const int bh = blockIdx.y;
  const int s0 = blockIdx.x * 64;
  const int tid = threadIdx.x;
  const int sr = tid >> 2, dc = (tid & 3) * 16;
  const size_t ib = ((size_t)bh * 2048 + s0 + sr) * 64 + dc;
  f16x8 v0 = *(const f16x8*)&Vh[ib];
  f16x8 v1 = *(const f16x8*)&Vh[ib + 8];
  *(f16x8*)&t[sr][dc]     = v0;
  *(f16x8*)&t[sr][dc + 8] = v1;
  __syncthreads();
  const int d = tid >> 2, sc = (tid & 3) * 16;
  f16x8 o0, o1;
  #pragma unroll
  for (int j = 0; j < 8; ++j) { o0[j] = t[sc + j][d]; o1[j] = t[sc + 8 + j][d]; }
  const size_t ob = ((size_t)bh * 64 + d) * 2048 + s0 + sc;
  *(f16x8*)&Vt[ob]     = o0;
  *(f16x8*)&Vt[ob + 8] = o1;
}

// ---------------- flash attention ----------------
// 2 waves/block, 32 q per wave (two 16-row B-frags), q-tile 64, KV tile 64.
// Round-2-style loop: __syncthreads barriers + register prefetch (full-iter distance).
// Pre-transposed V; padded LDS (all accesses <=2-way); vector P store; pairing (bx,31-bx).
__global__ __launch_bounds__(128) void attn_kernel(
    const f16* __restrict__ Q, const f16* __restrict__ K, const f16* __restrict__ Vt,
    f16* __restrict__ ctx)
{
  __shared__ __align__(16) f16 Ks[64 * 72];     // [kv][d], pad 72
  __shared__ __align__(16) f16 Vts[64 * 72];    // [d][kv], pad 72
  __shared__ __align__(16) f16 Ps[2][32 * 72];  // per-wave P [32 q][64 kv], pad 72
  __shared__ __align__(16) float abuf[2][32];
  __shared__ __align__(16) float lbuf[2][32];

  const int bh  = blockIdx.y;
  const int tid = threadIdx.x;
  const int wave = tid >> 6, lane = tid & 63;
  const int quad = lane >> 4, col = lane & 15;
  const int b = bh >> 4, h = bh & 15;
  const size_t base = (size_t)bh * 2048 * 64;
  const size_t vtb  = (size_t)bh * 64 * 2048;

  // staging map: 512 16B-chunks per tensor, 4 per thread
  int srow[4], sc8[4];
  #pragma unroll
  for (int i = 0; i < 4; ++i) {
    const int flat = tid + i * 128;
    srow[i] = flat >> 3;
    sc8[i]  = (flat & 7) * 8;
  }

  auto run_tile = [&](int qt) {
    const int q0 = qt * 64;
    const int qa = q0 + wave * 16;        // frag a: q in [qa, qa+16)
    const int qb = q0 + 32 + wave * 16;   // frag b
    const f16x8 bqa0 = *(const f16x8*)&Q[base + (size_t)(qa + col) * 64 + quad * 8];
    const f16x8 bqa1 = *(const f16x8*)&Q[base + (size_t)(qa + col) * 64 + 32 + quad * 8];
    const f16x8 bqb0 = *(const f16x8*)&Q[base + (size_t)(qb + col) * 64 + quad * 8];
    const f16x8 bqb1 = *(const f16x8*)&Q[base + (size_t)(qb + col) * 64 + 32 + quad * 8];

    f32x4 cta[4] = {}, ctb[4] = {};
    float ma = -INFINITY, la = 0.f, mb = -INFINITY, lb = 0.f;

    f16x8 kr[4], vr[4];
    auto gload = [&](int t) {
      #pragma unroll
      for (int i = 0; i < 4; ++i) {
        kr[i] = *(const f16x8*)&K[base + (size_t)(t * 64 + srow[i]) * 64 + sc8[i]];
        vr[i] = *(const f16x8*)&Vt[vtb + (size_t)srow[i] * 2048 + t * 64 + sc8[i]];
      }
    };
    gload(0);

    const int nIter = qt + 1;
    for (int t = 0; t < nIter; ++t) {
      __syncthreads();   // prev-iter LDS reads complete (vmcnt drain = own prefetch ready)
      #pragma unroll
      for (int i = 0; i < 4; ++i) {
        *(f16x8*)&Ks[srow[i] * 72 + sc8[i]]  = kr[i];
        *(f16x8*)&Vts[srow[i] * 72 + sc8[i]] = vr[i];
      }
      __syncthreads();
      if (t + 1 < nIter) gload(t + 1);   // full-iteration prefetch distance

      // S^T = K Q^T : lane holds S[kv=jt*16+quad*4+r][q=col(+16 for b)]
      f32x4 sa[4], sb[4];
      #pragma unroll
      for (int jt = 0; jt < 4; ++jt) {
        const int kro = (jt * 16 + col) * 72;
        const f16x8 ak0 = *(const f16x8*)&Ks[kro + quad * 8];
        const f16x8 ak1 = *(const f16x8*)&Ks[kro + 32 + quad * 8];
        f32x4 za = {}, zb = {};
        za = mfma16(ak0, bqa0, za); sa[jt] = mfma16(ak1, bqa1, za);
        zb = mfma16(ak0, bqb0, zb); sb[jt] = mfma16(ak1, bqb1, zb);
      }

      if (t == qt) {  // diagonal: causal mask (Q pre-scaled, s already in log2 units)
        #pragma unroll
        for (int jt = 0; jt < 4; ++jt) {
          const int kg = t * 64 + jt * 16 + quad * 4;
          #pragma unroll
          for (int r = 0; r < 4; ++r) {
            if (kg + r > qa + col) sa[jt][r] = -1e30f;
            if (kg + r > qb + col) sb[jt][r] = -1e30f;
          }
        }
      }

      // online softmax (exp2 domain); lane owns 16 kv of one q; reduce across quads
      const f16x2 one2 = {(_Float16)1.f, (_Float16)1.f};
      // frag a
      {
        float tm = fmaxf(fmaxf(sa[0][0], sa[0][1]), fmaxf(sa[0][2], sa[0][3]));
        #pragma unroll
        for (int jt = 1; jt < 4; ++jt)
          tm = fmaxf(tm, fmaxf(fmaxf(sa[jt][0], sa[jt][1]), fmaxf(sa[jt][2], sa[jt][3])));
        tm = fmaxf(tm, __shfl_xor(tm, 16));
        tm = fmaxf(tm, __shfl_xor(tm, 32));
        const float mnew = fmaxf(ma, tm);
        const float alpha = fexp2(ma - mnew);
        ma = mnew;
        float rs = 0.f;
        #pragma unroll
        for (int jt = 0; jt < 4; ++jt) {
          const f16x2 a01 = pkrtz(fexp2(sa[jt][0] - mnew), fexp2(sa[jt][1] - mnew));
          const f16x2 a23 = pkrtz(fexp2(sa[jt][2] - mnew), fexp2(sa[jt][3] - mnew));
          rs = dot2acc(a01, one2, rs);
          rs = dot2acc(a23, one2, rs);
          f16x4 pw; pw[0] = a01[0]; pw[1] = a01[1]; pw[2] = a23[0]; pw[3] = a23[1];
          *(f16x4*)&Ps[wave][col * 72 + jt * 16 + quad * 4] = pw;
        }
        rs += __shfl_xor(rs, 16);
        rs += __shfl_xor(rs, 32);
        la = la * alpha + rs;
        if (quad == 0) abuf[wave][col] = alpha;
      }
      // frag b
      {
        float tm = fmaxf(fmaxf(sb[0][0], sb[0][1]), fmaxf(sb[0][2], sb[0][3]));
        #pragma unroll
        for (int jt = 1; jt < 4; ++jt)
          tm = fmaxf(tm, fmaxf(fmaxf(sb[jt][0], sb[jt][1]), fmaxf(sb[jt][2], sb[jt][3])));
        tm = fmaxf(tm, __shfl_xor(tm, 16));
        tm = fmaxf(tm, __shfl_xor(tm, 32));
        const float mnew = fmaxf(mb, tm);
        const float alpha = fexp2(mb - mnew);
        mb = mnew;
        float rs = 0.f;
        #pragma unroll
        for (int jt = 0; jt < 4; ++jt) {
          const f16x2 a01 = pkrtz(fexp2(sb[jt][0] - mnew), fexp2(sb[jt][1] - mnew));
          const f16x2 a23 = pkrtz(fexp2(sb[jt][2] - mnew), fexp2(sb[jt][3] - mnew));
          rs = dot2acc(a01, one2, rs);
          rs = dot2acc(a23, one2, rs);
          f16x4 pw; pw[0] = a01[0]; pw[1] = a01[1]; pw[2] = a23[0]; pw[3] = a23[1];
          *(f16x4*)&Ps[wave][(16 + col) * 72 + jt * 16 + quad * 4] = pw;
        }
        rs += __shfl_xor(rs, 16);
        rs += __shfl_xor(rs, 32);
        lb = lb * alpha + rs;
        if (quad == 0) abuf[wave][16 + col] = alpha;
      }

      __asm__ volatile("s_waitcnt lgkmcnt(0)" ::: "memory");  // in-wave P/abuf RAW drain
      const f32x4 ava = *(const f32x4*)&abuf[wave][quad * 4];
      const f32x4 avb = *(const f32x4*)&abuf[wave][16 + quad * 4];
      #pragma unroll
      for (int jd = 0; jd < 4; ++jd) { cta[jd] *= ava; ctb[jd] *= avb; }

      // ctx += P V
      const f16x8 apa0 = *(const f16x8*)&Ps[wave][col * 72 + quad * 8];
      const f16x8 apa1 = *(const f16x8*)&Ps[wave][col * 72 + 32 + quad * 8];
      const f16x8 apb0 = *(const f16x8*)&Ps[wave][(16 + col) * 72 + quad * 8];
      const f16x8 apb1 = *(const f16x8*)&Ps[wave][(16 + col) * 72 + 32 + quad * 8];
      #pragma unroll
      for (int jd = 0; jd < 4; ++jd) {
        const int vro = (jd * 16 + col) * 72;
        const f16x8 bv0 = *(const f16x8*)&Vts[vro + quad * 8];
        const f16x8 bv1 = *(const f16x8*)&Vts[vro + 32 + quad * 8];
        cta[jd] = mfma16(apa1, bv1, mfma16(apa0, bv0, cta[jd]));
        ctb[jd] = mfma16(apb1, bv1, mfma16(apb0, bv0, ctb[jd]));
      }
    }

    // epilogue
    if (quad == 0) { lbuf[wave][col] = la; lbuf[wave][16 + col] = lb; }
    __asm__ volatile("s_waitcnt lgkmcnt(0)" ::: "memory");
    const f32x4 lva = *(const f32x4*)&lbuf[wave][quad * 4];
    const f32x4 lvb = *(const f32x4*)&lbuf[wave][16 + quad * 4];
    #pragma unroll
    for (int jd = 0; jd < 4; ++jd) {
      #pragma unroll
      for (int r = 0; r < 4; ++r) {
        const int qga = qa + quad * 4 + r;
        const int qgb = qb + quad * 4 + r;
        const int d = h * 64 + jd * 16 + col;
        ctx[((size_t)b * 2048 + qga) * 1024 + d] = (f16)(cta[jd][r] / lva[r]);
        ctx[((size_t)b * 2048 + qgb) * 1024 + d] = (f16)(ctb[jd][r] / lvb[r]);
      }
    }
  };

  run_tile(blockIdx.x);        // tiles 0..15
  run_tile(31 - blockIdx.x);   // tiles 31..16  -> uniform 33 kv-iters per block
}

// ---------------- O projection: 128x64 tile, BK=32 ----------------
__global__ __launch_bounds__(256) void gemm_o(
    const f16* __restrict__ A, const f16* __restrict__ B, const float* __restrict__ bias,
    float* __restrict__ Out)
{
  constexpr int K = 1024;
  __shared__ __align__(16) f16 As[128 * 32];
  __shared__ __align__(16) f16 Bs[64 * 32];
  const int tid  = threadIdx.x;
  const int wave = tid >> 6, lane = tid & 63;
  const int quad = lane >> 4, col = lane & 15;
  const int tile_m = blockIdx.y * 128, tile_n = blockIdx.x * 64;
  const int mb = wave * 32;
  const int srow = lane >> 2, scol = (lane & 3) * 8;
  const f16* gA = A + (size_t)(tile_m + wave * 32 + srow) * K + scol;
  const f16* gB = B + (size_t)(tile_n + wave * 16 + srow) * K + scol;
  f16* lA = As + wave * 1024;
  f16* lB = Bs + wave * 512;

  f32x4 acc[2][4] = {};
  for (int k0 = 0; k0 < K; k0 += 32) {
    gl2lds16(gA + k0,          lA);
    gl2lds16(gA + 16 * K + k0, lA + 512);
    gl2lds16(gB + k0,          lB);
    __syncthreads();
    f16x8 af[2], bf[4];
    #pragma unroll
    for (int i = 0; i < 2; ++i)
      af[i] = *(const f16x8*)&As[(mb + i * 16 + col) * 32 + quad * 8];
    #pragma unroll
    for (int j = 0; j < 4; ++j)
      bf[j] = *(const f16x8*)&Bs[(j * 16 + col) * 32 + quad * 8];
    #pragma unroll
    for (int i = 0; i < 2; ++i)
      #pragma unroll
      for (int j = 0; j < 4; ++j)
        acc[i][j] = mfma16(af[i], bf[j], acc[i][j]);
    __syncthreads();
  }

  #pragma unroll
  for (int j = 0; j < 4; ++j) {
    const int gn = tile_n + j * 16 + col;
    const float bvv = bias[gn];
    #pragma unroll
    for (int i = 0; i < 2; ++i) {
      #pragma unroll
      for (int r = 0; r < 4; ++r) {
        const int gm = tile_m + mb + i * 16 + quad * 4 + r;
        Out[(size_t)gm * 1024 + gn] = acc[i][j][r] + bvv;
      }
    }
  }
}

extern "C" void kernel_launch(void* const* d_in, const int* in_sizes, int n_in,
                              void* d_out, int out_size, void* d_ws, size_t ws_size,
                              hipStream_t stream)
{
  const float* x  = (const float*)d_in[0];
  const float* Wq = (const float*)d_in[1];
  const float* bq = (const float*)d_in[2];
  const float* Wk = (const float*)d_in[3];
  const float* bk = (const float*)d_in[4];
  const float* Wv = (const float*)d_in[5];
  const float* bv = (const float*)d_in[6];
  const float* Wo = (const float*)d_in[7];
  const float* bo = (const float*)d_in[8];
  float* out = (float*)d_out;

  f16* ws = (f16*)d_ws;
  const size_t M1 = 1048576;
  f16* xh    = ws;             // 4M halves
  f16* wqkvh = ws + 4  * M1;   // 3M
  f16* woh   = ws + 7  * M1;   // 1M
  f16* Qh    = ws + 8  * M1;   // 4M  [B,H,S,64] (pre-scaled)
  f16* Kh    = ws + 12 * M1;   // 4M  [B,H,S,64]
  f16* Vh    = ws + 16 * M1;   // 4M  [B,H,S,64]
  f16* Vth   = ws + 20 * M1;   // 4M  [B,H,64,S]
  f16* ctxh  = ws + 24 * M1;   // 4M  [B,S,D]

  cvt_kernel<<<dim3(2048, 5), 256, 0, stream>>>(x, Wq, Wk, Wv, Wo, xh, wqkvh, woh);
  gemm_qkv<<<dim3(24, 32), 256, 0, stream>>>(xh, wqkvh, bq, bk, bv, Qh, Kh, Vh);
  vtrans_kernel<<<dim3(32, 32), 256, 0, stream>>>(Vh, Vth);
  attn_kernel<<<dim3(16, 32), 128, 0, stream>>>(Qh, Kh, Vth, ctxh);
  gemm_o<<<dim3(16, 32), 256, 0, stream>>>(ctxh, woh, bo, out);
}